// Round 13
// baseline (57.054 us; speedup 1.0000x reference)
//
#include <hip/hip_runtime.h>

// STN forward, R13: persistent-block 8-phase pipeline (T3+T4 pattern).
// One 1024-thread block per CU (grid=256, XCD-swizzled); each block does
// 4 adjacent tiles x 2 channels = 8 phases over double-buffered LDS
// (2 x 52,224B). Per phase: barrier -> issue NEXT phase staging
// (global_load_lds, uniform 4/thread; tail waves write a dump slot so
// per-wave vmcnt counts stay exact) -> vmcnt(4|7) (never 0 mid-loop) ->
// barrier -> gather+store. Stage latency hides under compute; only the
// prologue stage is exposed. Geometry identical to R12 (verified).

constexpr int B = 2, C = 2, D = 128, H = 128, W = 128;
constexpr int HW  = H * W;
constexpr int DHW = D * HW;
constexpr int TD = 16, TH = 16, TW = 16;
constexpr int RD = 23, RH = 23, RWP = 24;    // region (halo d/h=3, w=-4/+3)
constexpr int CHF = RD * RH * RWP;           // 12696 floats
constexpr int CHG = CHF / 4;                 // 3174 16B granules
constexpr int NT  = 1024;
constexpr int BUFG = 3264;                   // 3200 data(+wave-spill) + 64 dump
constexpr int TPB = 4;                       // tiles per block

__device__ __forceinline__ void gload_lds16(const float* g, float* l) {
    __builtin_amdgcn_global_load_lds(
        (const __attribute__((address_space(1))) void*)g,
        (__attribute__((address_space(3))) void*)l, 16, 0, 0);
}

__global__ __launch_bounds__(NT) void stn_kernel(
    const float* __restrict__ image,
    const float* __restrict__ ddf,
    float* __restrict__ out)
{
    __shared__ float smem[2][BUFG * 4];      // 104,448 B total

    const int bid = blockIdx.x;              // 256 blocks
    const int cpx = gridDim.x >> 3;          // 32 (256 % 8 == 0 -> bijective)
    const int sb  = (bid & 7) * cpx + (bid >> 3);   // XCD-contiguous swizzle
    const int gt0 = sb * TPB;                // 4 consecutive tiles, same batch
    const int b   = gt0 >> 9;
    const float* imgb = image + (size_t)b * C * DHW;
    const float* ddfb = ddf + (size_t)b * 3 * DHW;
    float* outb = out + (size_t)b * C * DHW;
    const int tid = threadIdx.x;
    const int dl = tid >> 6, hl = (tid >> 2) & 15, wq = tid & 3;

    // tile id -> geometry (uniform per block -> SGPRs)
    auto tile_geom = [&](int gt, int& t0d, int& t0h, int& t0w,
                         int& lo_d, int& lo_h, int& lo_w,
                         int& hi_d, int& hi_h, int& hi_w) {
        int tb = gt & 511;
        t0d = (tb >> 6) * TD; t0h = ((tb >> 3) & 7) * TH; t0w = (tb & 7) * TW;
        lo_d = max(t0d - 3, 0); lo_h = max(t0h - 3, 0); lo_w = max(t0w - 4, 0);
        hi_d = min(lo_d + RD - 1, D - 1);
        hi_h = min(lo_h + RH - 1, H - 1);
        hi_w = min(lo_w + RWP - 1, W - 1);
    };

    // async stage one channel region into smem[buf]; EXACTLY 4 gloads/thread
    // (round 3: sources clamped, excess waves write the dump slot).
    auto issue_stage = [&](const float* src, int lo_d, int lo_h, int lo_w, int buf) {
#pragma unroll
        for (int i = 0; i < 4; ++i) {
            int g  = tid + i * NT;                        // 0..4095
            int gs = (i == 3) ? min(g, CHG - 1) : g;      // source granule
            int dg = (i == 3) ? min(g, 3200 + (tid & 63)) : g;  // LDS dest
            int row = gs / 6;
            int rw  = (gs - row * 6) * 4;
            int rd  = row / RH;
            int rh  = row - rd * RH;
            int off = min(lo_d + rd, D - 1) * HW + min(lo_h + rh, H - 1) * W
                    + min(lo_w + rw, W - 4);
            gload_lds16(src + off, &smem[buf][dg * 4]);
        }
    };

    // ---- prologue: ddf(tile0) + stage(tile0 ch0 -> buf0) = 7 vm ops ----
    int t0d, t0h, t0w, lo_d, lo_h, lo_w, hi_d, hi_h, hi_w;
    tile_geom(gt0, t0d, t0h, t0w, lo_d, lo_h, lo_w, hi_d, hi_h, hi_w);
    float4 nd, nh, nw;
    {
        int d_ = t0d + dl, h_ = t0h + hl, w_ = t0w + wq * 4;
        int si = d_ * HW + h_ * W + w_;
        nd = *reinterpret_cast<const float4*>(ddfb + si);
        nh = *reinterpret_cast<const float4*>(ddfb + DHW + si);
        nw = *reinterpret_cast<const float4*>(ddfb + 2 * DHW + si);
    }
    asm volatile("" ::: "memory");
    issue_stage(imgb, lo_d, lo_h, lo_w, 0);
    asm volatile("" ::: "memory");

#pragma unroll
    for (int t = 0; t < TPB; ++t) {
        // ======== phase A: compute tile t, ch0 (buf0) ========
        __builtin_amdgcn_s_barrier();                     // buf1 free
        issue_stage(imgb + DHW, lo_d, lo_h, lo_w, 1);     // ch1 -> buf1 (4)
        asm volatile("s_waitcnt vmcnt(4)" ::: "memory");  // ddf+ch0 drained
        __builtin_amdgcn_s_barrier();

        const int d_ = t0d + dl, h_ = t0h + hl, w4_ = t0w + wq * 4;
        const int sidx = d_ * HW + h_ * W + w4_;
        float cdk[4], chk[4], cwk[4];
        {
            const float a[4] = {nd.x, nd.y, nd.z, nd.w};
            const float e[4] = {nh.x, nh.y, nh.z, nh.w};
            const float c[4] = {nw.x, nw.y, nw.z, nw.w};
#pragma unroll
            for (int k = 0; k < 4; ++k) {
                cdk[k] = fminf(fmaxf((float)d_ + a[k], 0.0f), (float)(D - 1));
                chk[k] = fminf(fmaxf((float)h_ + e[k], 0.0f), (float)(H - 1));
                cwk[k] = fminf(fmaxf((float)(w4_ + k) + c[k], 0.0f), (float)(W - 1));
            }
        }

        // branchless LDS gather + rare global fixup + float4 store
        auto do_pass = [&](const float* sm, const float* gimg, float* optr) {
            float acc[4];
            int fb = 0;
#pragma unroll
            for (int k = 0; k < 4; ++k) {
                float cd = cdk[k], ch = chk[k], cw = cwk[k];
                float d0f = floorf(cd), h0f = floorf(ch), w0f = floorf(cw);
                float fd = cd - d0f, fh = ch - h0f, fw = cw - w0f;
                int d0 = (int)d0f, h0 = (int)h0f, w0 = (int)w0f;
                bool bad = (d0 < lo_d) | (d0 + 1 > hi_d)
                         | (h0 < lo_h) | (h0 + 1 > hi_h)
                         | (w0 < lo_w) | (w0 + 1 > hi_w);
                fb |= (int)bad << k;
                float gd = 1.0f - fd, gh = 1.0f - fh, gw = 1.0f - fw;
                float w00 = gh * gw, w01 = gh * fw, w10 = fh * gw, w11 = fh * fw;
                int i00 = ((d0 - lo_d) * RH + (h0 - lo_h)) * RWP + (w0 - lo_w);
                int i01 = i00 + RWP;
                int i10 = i00 + RH * RWP;
                int i11 = i10 + RWP;
                float p0 = sm[i00] * w00 + sm[i00 + 1] * w01
                         + sm[i01] * w10 + sm[i01 + 1] * w11;
                float p1 = sm[i10] * w00 + sm[i10 + 1] * w01
                         + sm[i11] * w10 + sm[i11 + 1] * w11;
                acc[k] = gd * p0 + fd * p1;
            }
            if (fb) {
#pragma unroll
                for (int k = 0; k < 4; ++k) {
                    if (fb & (1 << k)) {
                        float cd = cdk[k], ch = chk[k], cw = cwk[k];
                        float d0f = floorf(cd), h0f = floorf(ch), w0f = floorf(cw);
                        float fd = cd - d0f, fh = ch - h0f, fw = cw - w0f;
                        int d0 = (int)d0f, h0 = (int)h0f, w0 = (int)w0f;
                        int d1 = min(d0 + 1, D - 1);
                        int h1 = min(h0 + 1, H - 1);
                        int w1 = min(w0 + 1, W - 1);
                        float gd = 1.0f - fd, gh = 1.0f - fh, gw = 1.0f - fw;
                        float w00 = gh * gw, w01 = gh * fw, w10 = fh * gw, w11 = fh * fw;
                        int o00 = d0 * HW + h0 * W, o01 = d0 * HW + h1 * W;
                        int o10 = d1 * HW + h0 * W, o11 = d1 * HW + h1 * W;
                        float q0 = gimg[o00 + w0] * w00 + gimg[o00 + w1] * w01
                                 + gimg[o01 + w0] * w10 + gimg[o01 + w1] * w11;
                        float q1 = gimg[o10 + w0] * w00 + gimg[o10 + w1] * w01
                                 + gimg[o11 + w0] * w10 + gimg[o11 + w1] * w11;
                        acc[k] = gd * q0 + fd * q1;
                    }
                }
            }
            *reinterpret_cast<float4*>(optr) = make_float4(acc[0], acc[1], acc[2], acc[3]);
        };

        do_pass(&smem[0][0], imgb, outb + sidx);

        // ======== phase B: compute tile t, ch1 (buf1) ========
        __builtin_amdgcn_s_barrier();                     // buf0 reads done
        int n_t0d, n_t0h, n_t0w, n_lod, n_loh, n_low, n_hid, n_hih, n_hiw;
        if (t < TPB - 1) {
            tile_geom(gt0 + t + 1, n_t0d, n_t0h, n_t0w,
                      n_lod, n_loh, n_low, n_hid, n_hih, n_hiw);
            {   // ddf(tile t+1): 3 vm ops
                int d2 = n_t0d + dl, h2 = n_t0h + hl, w2 = n_t0w + wq * 4;
                int si = d2 * HW + h2 * W + w2;
                nd = *reinterpret_cast<const float4*>(ddfb + si);
                nh = *reinterpret_cast<const float4*>(ddfb + DHW + si);
                nw = *reinterpret_cast<const float4*>(ddfb + 2 * DHW + si);
            }
            asm volatile("" ::: "memory");
            issue_stage(imgb, n_lod, n_loh, n_low, 0);    // ch0(t+1) -> buf0 (4)
            asm volatile("s_waitcnt vmcnt(7)" ::: "memory");  // ch1 drained
        } else {
            asm volatile("s_waitcnt vmcnt(0)" ::: "memory");
        }
        __builtin_amdgcn_s_barrier();

        do_pass(&smem[1][0], imgb + DHW, outb + DHW + sidx);

        if (t < TPB - 1) {   // rotate geometry to tile t+1
            t0d = n_t0d; t0h = n_t0h; t0w = n_t0w;
            lo_d = n_lod; lo_h = n_loh; lo_w = n_low;
            hi_d = n_hid; hi_h = n_hih; hi_w = n_hiw;
        }
    }
}

extern "C" void kernel_launch(void* const* d_in, const int* in_sizes, int n_in,
                              void* d_out, int out_size, void* d_ws, size_t ws_size,
                              hipStream_t stream) {
    const float* image = (const float*)d_in[0];
    const float* ddf   = (const float*)d_in[1];
    float* out = (float*)d_out;

    int grid = (B * 512) / TPB;   // 256 blocks, 4 tiles each
    stn_kernel<<<grid, NT, 0, stream>>>(image, ddf, out);
}

// Round 14
// 55.762 us; speedup vs baseline: 1.0232x; 1.0232x over previous
//
#include <hip/hip_runtime.h>

// STN forward, LDS-tiled, one-channel buffer, two passes (R8 host structure).
// R14: gather via inline-asm ds_read2_b32 — the (w0,w1) corner pair is two
// ADJACENT floats, so 8 scalar ds_read_b32/voxel become 4 ds_read2_b32.
// All 16 read2s of a thread's 4 voxels issue back-to-back, then ONE
// s_waitcnt lgkmcnt(0) + sched_barrier(0) (rule #18), then all FMAs.
// Discriminator: time drops => DS issue/latency-bound; flat => bank-time.

constexpr int B = 2, C = 2, D = 128, H = 128, W = 128;
constexpr int HW  = H * W;
constexpr int DHW = D * HW;
constexpr int TD = 16, TH = 16, TW = 16;
constexpr int HALO = 4;
constexpr int RD = 25, RH = 25, RWP = 28;    // region (w padded: 7 granules)
constexpr int CHF = RD * RH * RWP;           // 17500 floats = 70,000 B
constexpr int CHG = CHF / 4;                 // 4375 16B granules
constexpr int NT = 1024;
constexpr int TAILN = CHG - 4 * NT;          // 279 tail granules (ds_write path)
constexpr int PLANE_B = RH * RWP * 4;        // 2800 B between d-planes

typedef float v2f __attribute__((ext_vector_type(2)));

__device__ __forceinline__ void gload_lds16(const float* g, float* l) {
    __builtin_amdgcn_global_load_lds(
        (const __attribute__((address_space(1))) void*)g,
        (__attribute__((address_space(3))) void*)l, 16, 0, 0);
}

__global__ __launch_bounds__(NT) void stn_kernel(
    const float* __restrict__ image,
    const float* __restrict__ ddf,
    float* __restrict__ out)
{
    __shared__ float smem[CHF];              // 70,000 B

    const int blk = blockIdx.x;
    const int b   = blk >> 9;
    const int tb  = blk & 511;
    const int t0d = (tb >> 6) * TD, t0h = ((tb >> 3) & 7) * TH, t0w = (tb & 7) * TW;
    const int lo_d = max(t0d - HALO, 0), lo_h = max(t0h - HALO, 0), lo_w = max(t0w - HALO, 0);
    const int hi_d = min(t0d + TD + HALO, D - 1);
    const int hi_h = min(t0h + TH + HALO, H - 1);
    const int hi_w = min(t0w + TW + HALO, W - 1);
    const float* imgb = image + (size_t)b * C * DHW;
    const int tid = threadIdx.x;
    const unsigned lds0 =
        (unsigned)(uintptr_t)(__attribute__((address_space(3))) void*)&smem[0];

    // ---- ddf loads FIRST ----
    const int dl = tid >> 6, hl = (tid >> 2) & 15, wq = tid & 3;
    const int d = t0d + dl, hh = t0h + hl, w4 = t0w + wq * 4;
    const int sidx = d * HW + hh * W + w4;
    const float* dp = ddf + (size_t)b * 3 * DHW + sidx;
    float4 fdd = *reinterpret_cast<const float4*>(dp);
    float4 fdh = *reinterpret_cast<const float4*>(dp + DHW);
    float4 fdw = *reinterpret_cast<const float4*>(dp + 2 * DHW);
    asm volatile("" ::: "memory");

    // granule g -> global offset (row-clamped at volume edge)
    auto gsrc_off = [&](int g) {
        int row = g / 7;
        int rw  = (g - row * 7) * 4;
        int rd  = row / RH;
        int rh  = row - rd * RH;
        return min(lo_d + rd, D - 1) * HW + min(lo_h + rh, H - 1) * W
             + min(lo_w + rw, W - 4);
    };

    // async stage: 4 full gload rounds + 279-granule ds_write tail
    auto issue_stage = [&](const float* src) {
#pragma unroll
        for (int i = 0; i < 4; ++i) {
            int g = tid + i * NT;                       // < 4096 < CHG
            gload_lds16(src + gsrc_off(g), &smem[g * 4]);
        }
        if (tid < TAILN) {
            int g = tid + 4 * NT;                       // 4096..4374
            float4 v = *reinterpret_cast<const float4*>(src + gsrc_off(g));
            *reinterpret_cast<float4*>(&smem[g * 4]) = v;
        }
    };

    issue_stage(imgb);                                  // ch0 in flight
    asm volatile("" ::: "memory");

    // clamped coords (persisted across both passes; 12 VGPR)
    float cdk[4], chk[4], cwk[4];
    {
        const float dd[4] = {fdd.x, fdd.y, fdd.z, fdd.w};
        const float dh[4] = {fdh.x, fdh.y, fdh.z, fdh.w};
        const float dw[4] = {fdw.x, fdw.y, fdw.z, fdw.w};
#pragma unroll
        for (int k = 0; k < 4; ++k) {
            cdk[k] = fminf(fmaxf((float)d + dd[k], 0.0f), (float)(D - 1));
            chk[k] = fminf(fmaxf((float)hh + dh[k], 0.0f), (float)(H - 1));
            cwk[k] = fminf(fmaxf((float)(w4 + k) + dw[k], 0.0f), (float)(W - 1));
        }
    }

    // one pass: 16x ds_read2_b32 batch -> one lgkmcnt wait -> FMAs;
    // rare global fixup for out-of-region coords; float4 store.
    auto do_pass = [&](const float* gimg, float* optr) {
        unsigned a0[4], a1[4];
        float W00[4], W01[4], W10[4], W11[4], GD[4], FD[4];
        int fb = 0;
#pragma unroll
        for (int k = 0; k < 4; ++k) {
            float cd = cdk[k], ch = chk[k], cw = cwk[k];
            float d0f = floorf(cd), h0f = floorf(ch), w0f = floorf(cw);
            float fd = cd - d0f, fh = ch - h0f, fw = cw - w0f;
            int d0 = (int)d0f, h0 = (int)h0f, w0 = (int)w0f;
            bool bad = (d0 < lo_d) | (d0 + 1 > hi_d)
                     | (h0 < lo_h) | (h0 + 1 > hi_h)
                     | (w0 < lo_w) | (w0 + 1 > hi_w);
            fb |= (int)bad << k;
            float gh = 1.0f - fh, gw = 1.0f - fw;
            W00[k] = gh * gw; W01[k] = gh * fw; W10[k] = fh * gw; W11[k] = fh * fw;
            GD[k] = 1.0f - fd; FD[k] = fd;
            int i00 = ((d0 - lo_d) * RH + (h0 - lo_h)) * RWP + (w0 - lo_w);
            a0[k] = lds0 + (unsigned)(i00 * 4);
            a1[k] = a0[k] + PLANE_B;
        }
        v2f r00[4], r01[4], r10[4], r11[4];
#pragma unroll
        for (int k = 0; k < 4; ++k) {
            asm volatile("ds_read2_b32 %0, %1 offset0:0 offset1:1"
                         : "=v"(r00[k]) : "v"(a0[k]));
            asm volatile("ds_read2_b32 %0, %1 offset0:28 offset1:29"
                         : "=v"(r01[k]) : "v"(a0[k]));
            asm volatile("ds_read2_b32 %0, %1 offset0:0 offset1:1"
                         : "=v"(r10[k]) : "v"(a1[k]));
            asm volatile("ds_read2_b32 %0, %1 offset0:28 offset1:29"
                         : "=v"(r11[k]) : "v"(a1[k]));
        }
        asm volatile("s_waitcnt lgkmcnt(0)" ::: "memory");
        __builtin_amdgcn_sched_barrier(0);

        float acc[4];
#pragma unroll
        for (int k = 0; k < 4; ++k) {
            float p0 = r00[k].x * W00[k] + r00[k].y * W01[k]
                     + r01[k].x * W10[k] + r01[k].y * W11[k];
            float p1 = r10[k].x * W00[k] + r10[k].y * W01[k]
                     + r11[k].x * W10[k] + r11[k].y * W11[k];
            acc[k] = GD[k] * p0 + FD[k] * p1;
        }
        if (fb) {                            // rare: exact global recompute
#pragma unroll
            for (int k = 0; k < 4; ++k) {
                if (fb & (1 << k)) {
                    float cd = cdk[k], ch = chk[k], cw = cwk[k];
                    float d0f = floorf(cd), h0f = floorf(ch), w0f = floorf(cw);
                    float fd = cd - d0f, fh = ch - h0f, fw = cw - w0f;
                    int d0 = (int)d0f, h0 = (int)h0f, w0 = (int)w0f;
                    int d1 = min(d0 + 1, D - 1);
                    int h1 = min(h0 + 1, H - 1);
                    int w1 = min(w0 + 1, W - 1);
                    float gd = 1.0f - fd, gh = 1.0f - fh, gw = 1.0f - fw;
                    float w00 = gh * gw, w01 = gh * fw, w10 = fh * gw, w11 = fh * fw;
                    int o00 = d0 * HW + h0 * W, o01 = d0 * HW + h1 * W;
                    int o10 = d1 * HW + h0 * W, o11 = d1 * HW + h1 * W;
                    float q0 = gimg[o00 + w0] * w00 + gimg[o00 + w1] * w01
                             + gimg[o01 + w0] * w10 + gimg[o01 + w1] * w11;
                    float q1 = gimg[o10 + w0] * w00 + gimg[o10 + w1] * w01
                             + gimg[o11 + w0] * w10 + gimg[o11 + w1] * w11;
                    acc[k] = gd * q0 + fd * q1;
                }
            }
        }
        *reinterpret_cast<float4*>(optr) = make_float4(acc[0], acc[1], acc[2], acc[3]);
    };

    // ---- pass 0 ----
    asm volatile("s_waitcnt vmcnt(0) lgkmcnt(0)" ::: "memory");
    __builtin_amdgcn_s_barrier();
    do_pass(imgb, out + ((size_t)b * C + 0) * DHW + sidx);

    __builtin_amdgcn_s_barrier();                       // ch0 reads done
    asm volatile("" ::: "memory");

    // ---- pass 1 ----
    issue_stage(imgb + DHW);
    asm volatile("s_waitcnt vmcnt(0) lgkmcnt(0)" ::: "memory");
    __builtin_amdgcn_s_barrier();
    do_pass(imgb + DHW, out + ((size_t)b * C + 1) * DHW + sidx);
}

extern "C" void kernel_launch(void* const* d_in, const int* in_sizes, int n_in,
                              void* d_out, int out_size, void* d_ws, size_t ws_size,
                              hipStream_t stream) {
    const float* image = (const float*)d_in[0];
    const float* ddf   = (const float*)d_in[1];
    float* out = (float*)d_out;

    int grid = B * 512;   // 8x8x8 tiles of 16^3 per batch
    stn_kernel<<<grid, NT, 0, stream>>>(image, ddf, out);
}

// Round 15
// 47.235 us; speedup vs baseline: 1.2079x; 1.1805x over previous
//
#include <hip/hip_runtime.h>

// STN forward, R15: full-W slab tiles to fix HBM access pattern.
// Theory: all prior variants pinned at ~2.6 TB/s because staging reads were
// scattered 112B row fragments. Tile 8x8x128 (full W), halo d/h=3 -> staged
// region 15x15x128 floats (115,200B): staging reads are 15 contiguous ~7.7KB
// slabs per d-plane (h-rows adjacent in memory) = streaming DRAM pattern.
// w stays in-region (border clamp keeps w in [0,127]); only d/h jitter >3
// (~0.5%) takes the exact global fixup path. Two channel passes over one
// buffer (R8 structure). XCD swizzle: h-adjacent tiles share an XCD L2.

constexpr int B = 2, C = 2, D = 128, H = 128, W = 128;
constexpr int HW  = H * W;
constexpr int DHW = D * HW;
constexpr int TDd = 8, TDh = 8;              // tile: 8 x 8 x 128
constexpr int RD = 15, RH = 15;              // region extents (halo 3 + clamp row)
constexpr int CHF = RD * RH * W;             // 28,800 floats = 115,200 B
constexpr int CHG = CHF / 4;                 // 7,200 16B granules
constexpr int NT = 1024;
constexpr int NFULL = 7;                     // 7*1024 = 7168 granules
constexpr int TAILN = CHG - NFULL * NT;      // 32 tail granules
constexpr int ROWSTRIDE = W;                 // 128 dwords
constexpr int PLANESTRIDE = RH * W;          // 1920 dwords

__device__ __forceinline__ void gload_lds16(const float* g, float* l) {
    __builtin_amdgcn_global_load_lds(
        (const __attribute__((address_space(1))) void*)g,
        (__attribute__((address_space(3))) void*)l, 16, 0, 0);
}

__global__ __launch_bounds__(NT) void stn_kernel(
    const float* __restrict__ image,
    const float* __restrict__ ddf,
    float* __restrict__ out)
{
    __shared__ float smem[CHF];              // 115,200 B

    // XCD-contiguous swizzle (512 blocks, 512%8==0 -> bijective)
    const int bid = blockIdx.x;
    const int cpx = gridDim.x >> 3;          // 64
    const int blk = (bid & 7) * cpx + (bid >> 3);

    const int b   = blk >> 8;                // 256 tiles per batch (16d x 16h)
    const int tb  = blk & 255;
    const int t0d = (tb >> 4) * TDd, t0h = (tb & 15) * TDh;
    const int lo_d = max(t0d - 3, 0), lo_h = max(t0h - 3, 0);
    const int hi_d = min(lo_d + RD - 1, D - 1);
    const int hi_h = min(lo_h + RH - 1, H - 1);
    const float* imgb = image + (size_t)b * C * DHW;
    const int tid = threadIdx.x;

    // ---- ddf loads FIRST: 8 voxels/thread = (dl,hl,w4) and (dl+4,hl,w4) ----
    const int dl = tid >> 8, hl = (tid >> 5) & 7, wq = tid & 31;
    const int d0_ = t0d + dl, h_ = t0h + hl, w4 = wq * 4;
    const int sidx0 = d0_ * HW + h_ * W + w4;
    const int sidx1 = sidx0 + 4 * HW;        // d + 4
    const float* dp = ddf + (size_t)b * 3 * DHW;
    float4 f0d = *reinterpret_cast<const float4*>(dp + sidx0);
    float4 f1d = *reinterpret_cast<const float4*>(dp + sidx1);
    float4 f0h = *reinterpret_cast<const float4*>(dp + DHW + sidx0);
    float4 f1h = *reinterpret_cast<const float4*>(dp + DHW + sidx1);
    float4 f0w = *reinterpret_cast<const float4*>(dp + 2 * DHW + sidx0);
    float4 f1w = *reinterpret_cast<const float4*>(dp + 2 * DHW + sidx1);
    asm volatile("" ::: "memory");

    // granule g -> global offset; rows are full W (contiguous 512B), rows
    // adjacent in h -> per-d-plane the 15 rows form one contiguous slab.
    auto gsrc_off = [&](int g) {
        int row = g >> 5;                    // 32 granules per row
        int rw  = (g & 31) << 2;
        int rd  = row / RH;
        int rh  = row - rd * RH;
        return min(lo_d + rd, D - 1) * HW + min(lo_h + rh, H - 1) * W + rw;
    };

    // async stage: 7 full gload rounds + 32-granule ds_write tail
    auto issue_stage = [&](const float* src) {
#pragma unroll
        for (int i = 0; i < NFULL; ++i) {
            int g = tid + i * NT;                       // < 7168 < CHG
            gload_lds16(src + gsrc_off(g), &smem[g * 4]);
        }
        if (tid < TAILN) {
            int g = tid + NFULL * NT;                   // 7168..7199
            float4 v = *reinterpret_cast<const float4*>(src + gsrc_off(g));
            *reinterpret_cast<float4*>(&smem[g * 4]) = v;
        }
    };

    issue_stage(imgb);                                  // ch0 in flight
    asm volatile("" ::: "memory");

    // clamped coords, 8 voxels (24 VGPR, persisted across both passes)
    float cdk[8], chk[8], cwk[8];
    {
        const float a0[4] = {f0d.x, f0d.y, f0d.z, f0d.w};
        const float a1[4] = {f1d.x, f1d.y, f1d.z, f1d.w};
        const float b0[4] = {f0h.x, f0h.y, f0h.z, f0h.w};
        const float b1[4] = {f1h.x, f1h.y, f1h.z, f1h.w};
        const float c0[4] = {f0w.x, f0w.y, f0w.z, f0w.w};
        const float c1[4] = {f1w.x, f1w.y, f1w.z, f1w.w};
#pragma unroll
        for (int k = 0; k < 4; ++k) {
            cdk[k]     = fminf(fmaxf((float)d0_ + a0[k], 0.0f), (float)(D - 1));
            cdk[4 + k] = fminf(fmaxf((float)(d0_ + 4) + a1[k], 0.0f), (float)(D - 1));
            chk[k]     = fminf(fmaxf((float)h_ + b0[k], 0.0f), (float)(H - 1));
            chk[4 + k] = fminf(fmaxf((float)h_ + b1[k], 0.0f), (float)(H - 1));
            cwk[k]     = fminf(fmaxf((float)(w4 + k) + c0[k], 0.0f), (float)(W - 1));
            cwk[4 + k] = fminf(fmaxf((float)(w4 + k) + c1[k], 0.0f), (float)(W - 1));
        }
    }

    // one pass: branchless LDS gather of 8 voxels + rare global fixup + store
    auto do_pass = [&](const float* gimg, float* obase) {
#pragma unroll
        for (int r = 0; r < 2; ++r) {
            float acc[4];
            int fb = 0;
#pragma unroll
            for (int k = 0; k < 4; ++k) {
                int v = r * 4 + k;
                float cd = cdk[v], ch = chk[v], cw = cwk[v];
                float d0f = floorf(cd), h0f = floorf(ch), w0f = floorf(cw);
                float fd = cd - d0f, fh = ch - h0f, fw = cw - w0f;
                int d0 = (int)d0f, h0 = (int)h0f, w0 = (int)w0f;
                bool bad = (d0 < lo_d) | (d0 + 1 > hi_d)
                         | (h0 < lo_h) | (h0 + 1 > hi_h)
                         | (w0 >= W - 1);               // w edge -> fixup
                fb |= (int)bad << k;
                float gd = 1.0f - fd, gh = 1.0f - fh, gw = 1.0f - fw;
                float w00 = gh * gw, w01 = gh * fw, w10 = fh * gw, w11 = fh * fw;
                int i00 = ((d0 - lo_d) * RH + (h0 - lo_h)) * ROWSTRIDE + w0;
                int i01 = i00 + ROWSTRIDE;              // h0+1
                int i10 = i00 + PLANESTRIDE;            // d0+1
                int i11 = i10 + ROWSTRIDE;
                float p0 = smem[i00] * w00 + smem[i00 + 1] * w01
                         + smem[i01] * w10 + smem[i01 + 1] * w11;
                float p1 = smem[i10] * w00 + smem[i10 + 1] * w01
                         + smem[i11] * w10 + smem[i11 + 1] * w11;
                acc[k] = gd * p0 + fd * p1;             // garbage if bad
            }
            if (fb) {                                   // rare exact fixup
#pragma unroll
                for (int k = 0; k < 4; ++k) {
                    if (fb & (1 << k)) {
                        int v = r * 4 + k;
                        float cd = cdk[v], ch = chk[v], cw = cwk[v];
                        float d0f = floorf(cd), h0f = floorf(ch), w0f = floorf(cw);
                        float fd = cd - d0f, fh = ch - h0f, fw = cw - w0f;
                        int d0 = (int)d0f, h0 = (int)h0f, w0 = (int)w0f;
                        int d1 = min(d0 + 1, D - 1);
                        int h1 = min(h0 + 1, H - 1);
                        int w1 = min(w0 + 1, W - 1);
                        float gd = 1.0f - fd, gh = 1.0f - fh, gw = 1.0f - fw;
                        float w00 = gh * gw, w01 = gh * fw, w10 = fh * gw, w11 = fh * fw;
                        int o00 = d0 * HW + h0 * W, o01 = d0 * HW + h1 * W;
                        int o10 = d1 * HW + h0 * W, o11 = d1 * HW + h1 * W;
                        float q0 = gimg[o00 + w0] * w00 + gimg[o00 + w1] * w01
                                 + gimg[o01 + w0] * w10 + gimg[o01 + w1] * w11;
                        float q1 = gimg[o10 + w0] * w00 + gimg[o10 + w1] * w01
                                 + gimg[o11 + w0] * w10 + gimg[o11 + w1] * w11;
                        acc[k] = gd * q0 + fd * q1;
                    }
                }
            }
            *reinterpret_cast<float4*>(obase + (r ? sidx1 : sidx0)) =
                make_float4(acc[0], acc[1], acc[2], acc[3]);
        }
    };

    // ---- pass 0 ----
    asm volatile("s_waitcnt vmcnt(0) lgkmcnt(0)" ::: "memory");
    __builtin_amdgcn_s_barrier();
    do_pass(imgb, out + ((size_t)b * C + 0) * DHW);

    __builtin_amdgcn_s_barrier();                       // ch0 reads done
    asm volatile("" ::: "memory");

    // ---- pass 1 ----
    issue_stage(imgb + DHW);
    asm volatile("s_waitcnt vmcnt(0) lgkmcnt(0)" ::: "memory");
    __builtin_amdgcn_s_barrier();
    do_pass(imgb + DHW, out + ((size_t)b * C + 1) * DHW);
}

extern "C" void kernel_launch(void* const* d_in, const int* in_sizes, int n_in,
                              void* d_out, int out_size, void* d_ws, size_t ws_size,
                              hipStream_t stream) {
    const float* image = (const float*)d_in[0];
    const float* ddf   = (const float*)d_in[1];
    float* out = (float*)d_out;

    int grid = B * 256;   // 16x16 tiles of 8x8x128 per batch = 512 blocks
    stn_kernel<<<grid, NT, 0, stream>>>(image, ddf, out);
}